// Round 7
// baseline (708.853 us; speedup 1.0000x reference)
//
#include <hip/hip_runtime.h>

#define NNODES 50000
#define NEDGES 800000
#define NGRAPHS 1000
#define BN_EPS 1e-5f
#define MPAD 50048   // 391 * 128

typedef unsigned short us_t;
typedef us_t us8 __attribute__((ext_vector_type(8)));
typedef us_t us4 __attribute__((ext_vector_type(4)));
typedef __bf16 bf16x8 __attribute__((ext_vector_type(8)));
typedef float f32x4 __attribute__((ext_vector_type(4)));

__device__ __forceinline__ float b2f(us_t u) {
    union { unsigned int i; float f; } v;
    v.i = ((unsigned int)u) << 16;
    return v.f;
}
__device__ __forceinline__ us_t f2b(float x) {
    unsigned int u = __float_as_uint(x);
    unsigned int r = u + 0x7FFFu + ((u >> 16) & 1u);
    return (us_t)(r >> 16);
}
__device__ __forceinline__ bf16x8 as_bf(us8 v) {
    union { us8 u; bf16x8 b; } c;
    c.u = v;
    return c.b;
}

// ================= elementwise =================

__global__ void zero_f32(float* __restrict__ p, int n) {
    int i = blockIdx.x * blockDim.x + threadIdx.x;
    if (i < n) p[i] = 0.f;
}

// ================= CSR build =================

__global__ void csr_hist(const int* __restrict__ dst, int* __restrict__ deg, int E) {
    int e = blockIdx.x * blockDim.x + threadIdx.x;
    if (e < E) atomicAdd(&deg[dst[e]], 1);
}

__global__ void csr_scan1(const int* __restrict__ deg, int* __restrict__ tmpscan,
                          int* __restrict__ chunkTot, int n) {
    __shared__ int sm[1024];
    int i = blockIdx.x * 1024 + threadIdx.x;
    int v = (i < n) ? deg[i] : 0;
    sm[threadIdx.x] = v;
    __syncthreads();
    for (int off = 1; off < 1024; off <<= 1) {
        int add = (threadIdx.x >= off) ? sm[threadIdx.x - off] : 0;
        __syncthreads();
        sm[threadIdx.x] += add;
        __syncthreads();
    }
    if (i < n) tmpscan[i] = sm[threadIdx.x];
    if (threadIdx.x == 1023) chunkTot[blockIdx.x] = sm[1023];
}

__global__ void csr_scan2(int* __restrict__ chunkTot, int nchunks) {
    if (threadIdx.x == 0 && blockIdx.x == 0) {
        int run = 0;
        for (int c = 0; c < nchunks; c++) {
            int t = chunkTot[c];
            chunkTot[c] = run;
            run += t;
        }
    }
}

__global__ void csr_scan3(const int* __restrict__ deg, const int* __restrict__ tmpscan,
                          const int* __restrict__ chunkTot, int* __restrict__ rowptr,
                          int* __restrict__ cursor, int n) {
    int i = blockIdx.x * blockDim.x + threadIdx.x;
    if (i < n) {
        int inc = tmpscan[i] + chunkTot[i >> 10];
        rowptr[i + 1] = inc;
        cursor[i] = inc - deg[i];
        if (i == 0) rowptr[0] = 0;
    }
}

__global__ void csr_fill(const int* __restrict__ src, const int* __restrict__ dst,
                         int* __restrict__ cursor, int* __restrict__ eidx, int E) {
    int e = blockIdx.x * blockDim.x + threadIdx.x;
    if (e < E) {
        int pos = atomicAdd(&cursor[dst[e]], 1);
        eidx[pos] = src[e];
    }
}

// ================= all weight converts in one kernel: W[K][N] -> Wt[N][K] bf16 ==========

__global__ void wt_convert_all(const float* __restrict__ w2, const float* __restrict__ w3,
                               const float* __restrict__ w4, const float* __restrict__ w5,
                               const float* __restrict__ w6,
                               us_t* __restrict__ o2, us_t* __restrict__ o3,
                               us_t* __restrict__ o4, us_t* __restrict__ o5,
                               us_t* __restrict__ o6) {
    int i = blockIdx.x * blockDim.x + threadIdx.x;
    if (i < 16384) {                       // 128x128
        int k = i >> 7, n = i & 127;
        o2[n * 128 + k] = f2b(w2[i]);
    } else if (i < 49152) {                // 128x256
        int j = i - 16384; int k = j >> 8, n = j & 255;
        o3[n * 128 + k] = f2b(w3[j]);
    } else if (i < 114688) {               // 256x256
        int j = i - 49152; int k = j >> 8, n = j & 255;
        o4[n * 256 + k] = f2b(w4[j]);
    } else if (i < 180224) {
        int j = i - 114688; int k = j >> 8, n = j & 255;
        o5[n * 256 + k] = f2b(w5[j]);
    } else if (i < 245760) {
        int j = i - 180224; int k = j >> 8, n = j & 255;
        o6[n * 256 + k] = f2b(w6[j]);
    }
}

// ================= GIN gather (bf16 in/out, fp32 accum, 4x unrolled) =================

template <int F>
__global__ void gin_gather_bf(const us_t* __restrict__ h, const int* __restrict__ rowptr,
                              const int* __restrict__ eidx, us_t* __restrict__ out) {
    constexpr int TPN = F / 4;
    constexpr int NPB = 256 / TPN;
    int ln = threadIdx.x / TPN;
    int fp = threadIdx.x % TPN;
    int n = blockIdx.x * NPB + ln;
    if (n >= NNODES) return;
    const us_t* hf = h + fp * 4;
    us4 v = *(const us4*)&hf[(size_t)n * F];
    float a0 = b2f(v[0]), a1 = b2f(v[1]), a2 = b2f(v[2]), a3 = b2f(v[3]);
    int p0 = rowptr[n], p1 = rowptr[n + 1];
    int p = p0;
    for (; p + 4 <= p1; p += 4) {
        int s0 = eidx[p], s1 = eidx[p + 1], s2 = eidx[p + 2], s3 = eidx[p + 3];
        us4 u0 = *(const us4*)&hf[(size_t)s0 * F];
        us4 u1 = *(const us4*)&hf[(size_t)s1 * F];
        us4 u2 = *(const us4*)&hf[(size_t)s2 * F];
        us4 u3 = *(const us4*)&hf[(size_t)s3 * F];
        a0 += b2f(u0[0]) + b2f(u1[0]) + b2f(u2[0]) + b2f(u3[0]);
        a1 += b2f(u0[1]) + b2f(u1[1]) + b2f(u2[1]) + b2f(u3[1]);
        a2 += b2f(u0[2]) + b2f(u1[2]) + b2f(u2[2]) + b2f(u3[2]);
        a3 += b2f(u0[3]) + b2f(u1[3]) + b2f(u2[3]) + b2f(u3[3]);
    }
    for (; p < p1; p++) {
        int s = eidx[p];
        us4 u = *(const us4*)&hf[(size_t)s * F];
        a0 += b2f(u[0]); a1 += b2f(u[1]); a2 += b2f(u[2]); a3 += b2f(u[3]);
    }
    us4 o;
    o[0] = f2b(a0); o[1] = f2b(a1); o[2] = f2b(a2); o[3] = f2b(a3);
    *(us4*)&out[(size_t)n * F + fp * 4] = o;
}

// F=11 fp32 gather (input features)
__global__ void gin_gather11(const float* __restrict__ x, const int* __restrict__ rowptr,
                             const int* __restrict__ eidx, float* __restrict__ out) {
    int local = threadIdx.x >> 4;
    int lane = threadIdx.x & 15;
    int n = blockIdx.x * 16 + local;
    if (n >= NNODES) return;
    int p0 = rowptr[n], p1 = rowptr[n + 1];
    float acc = (lane < 11) ? x[n * 11 + lane] : 0.f;
    for (int p = p0; p < p1; p++) {
        int src = eidx[p];
        if (lane < 11) acc += x[src * 11 + lane];
    }
    if (lane < 11) out[n * 11 + lane] = acc;
}

// ================= layer-1 GEMM: [M,11] fp32 @ [11,128] + b -> fp32 + stats ==========

__global__ __launch_bounds__(256) void gemm11(const float* __restrict__ A,
                                              const float* __restrict__ W,
                                              const float* __restrict__ b,
                                              float* __restrict__ C,
                                              float* __restrict__ sums,
                                              float* __restrict__ sumsq) {
    __shared__ float sW[11 * 128];
    __shared__ float sArows[64 * 11];
    int tid = threadIdx.x;
    for (int i = tid; i < 11 * 128; i += 256) sW[i] = W[i];
    int r0 = blockIdx.x * 64;
    for (int i = tid; i < 64 * 11; i += 256) {
        int r = i / 11, c = i - r * 11;
        sArows[i] = (r0 + r < NNODES) ? A[(r0 + r) * 11 + c] : 0.f;
    }
    __syncthreads();
    int col = tid & 127;
    int half = tid >> 7;
    float bias = b[col];
    float cs = 0.f, cq = 0.f;
    for (int rr = half * 32; rr < half * 32 + 32; rr++) {
        int row = r0 + rr;
        if (row < NNODES) {
            float acc = bias;
            #pragma unroll
            for (int k = 0; k < 11; k++) acc += sArows[rr * 11 + k] * sW[k * 128 + col];
            C[(size_t)row * 128 + col] = acc;
            cs += acc;
            cq += acc * acc;
        }
    }
    __syncthreads();
    sArows[tid] = cs;
    sArows[256 + tid] = cq;
    __syncthreads();
    if (tid < 128) {
        atomicAdd(&sums[tid], sArows[tid] + sArows[tid + 128]);
        atomicAdd(&sumsq[tid], sArows[256 + tid] + sArows[256 + tid + 128]);
    }
}

// ================= MFMA GEMM v3 (no B LDS — B is L2-resident) =================
// C[M,N] fp32 = A'[M,K_] @ Wt[N,K_]^T + bias, + column stats.
// AMODE 0: A bf16. AMODE 1: A fp32, A' = relu(A*s+t)->bf16, (s,t) from raw stats.
// Block 128 rows x 128 cols, 4 waves of 64x64. Both A and B fragments load
// straight from global (b128); only LDS is the 2KB s/t table -> high occupancy,
// zero K-loop barriers, zero bank conflicts.

template <int K_, int AMODE>
__global__ __launch_bounds__(256, 4) void gemm_v3(
    const void* __restrict__ Ap, const us_t* __restrict__ Wt,
    const float* __restrict__ bias,
    const float* __restrict__ sums_in, const float* __restrict__ sumsq_in,
    const float* __restrict__ gma, const float* __restrict__ bet, float invM,
    float* __restrict__ C, float* __restrict__ sums, float* __restrict__ sumsq,
    int M, int N) {
    __shared__ float sST[2 * K_];          // [s | t], 1-2 KB

    const int tid = threadIdx.x;
    const int lane = tid & 63;
    const int wave = tid >> 6;
    const int wm = wave >> 1, wn = wave & 1;
    const int bn = blockIdx.x * 128;
    const int bm = blockIdx.y * 128;
    const int lrow = lane & 15, lquad = lane >> 4;

    if (AMODE == 1) {
        if (tid < K_) {
            float m = sums_in[tid] * invM;
            float va = sumsq_in[tid] * invM - m * m;
            float sc = gma[tid] * rsqrtf(va + BN_EPS);
            sST[tid] = sc;
            sST[K_ + tid] = bet[tid] - m * sc;
        }
        __syncthreads();
    }

    f32x4 acc[4][4] = {};

    size_t arow[4];
    #pragma unroll
    for (int i = 0; i < 4; i++) arow[i] = (size_t)(bm + wm * 64 + i * 16 + lrow) * K_;
    size_t brow[4];
    #pragma unroll
    for (int j = 0; j < 4; j++) brow[j] = (size_t)(bn + wn * 64 + j * 16 + lrow) * K_;

    #pragma unroll
    for (int kt = 0; kt < K_ / 32; kt++) {
        const int kq = kt * 32 + lquad * 8;
        bf16x8 af[4], bfr[4];
        if (AMODE == 0) {
            const us_t* A = (const us_t*)Ap;
            #pragma unroll
            for (int i = 0; i < 4; i++)
                af[i] = as_bf(*(const us8*)&A[arow[i] + kq]);
        } else {
            const float* A = (const float*)Ap;
            float4 s0 = *(const float4*)&sST[kq];
            float4 s1 = *(const float4*)&sST[kq + 4];
            float4 t0 = *(const float4*)&sST[K_ + kq];
            float4 t1 = *(const float4*)&sST[K_ + kq + 4];
            #pragma unroll
            for (int i = 0; i < 4; i++) {
                const float* ar = &A[arow[i] + kq];
                float4 v0 = *(const float4*)ar;
                float4 v1 = *(const float4*)(ar + 4);
                union { us8 u; bf16x8 b; } cv;
                cv.u[0] = f2b(fmaxf(0.f, v0.x * s0.x + t0.x));
                cv.u[1] = f2b(fmaxf(0.f, v0.y * s0.y + t0.y));
                cv.u[2] = f2b(fmaxf(0.f, v0.z * s0.z + t0.z));
                cv.u[3] = f2b(fmaxf(0.f, v0.w * s0.w + t0.w));
                cv.u[4] = f2b(fmaxf(0.f, v1.x * s1.x + t1.x));
                cv.u[5] = f2b(fmaxf(0.f, v1.y * s1.y + t1.y));
                cv.u[6] = f2b(fmaxf(0.f, v1.z * s1.z + t1.z));
                cv.u[7] = f2b(fmaxf(0.f, v1.w * s1.w + t1.w));
                af[i] = cv.b;
            }
        }
        #pragma unroll
        for (int j = 0; j < 4; j++)
            bfr[j] = as_bf(*(const us8*)&Wt[brow[j] + kq]);
        #pragma unroll
        for (int i = 0; i < 4; i++)
            #pragma unroll
            for (int j = 0; j < 4; j++)
                acc[i][j] = __builtin_amdgcn_mfma_f32_16x16x32_bf16(af[i], bfr[j],
                                                                    acc[i][j], 0, 0, 0);
    }

    // ---- epilogue: bias, fp32 store, fused column stats ----
    #pragma unroll
    for (int j = 0; j < 4; j++) {
        int col = bn + wn * 64 + j * 16 + lrow;
        float bcol = bias[col];
        float cs = 0.f, cq = 0.f;
        #pragma unroll
        for (int i = 0; i < 4; i++) {
            int rb = bm + wm * 64 + i * 16 + lquad * 4;
            #pragma unroll
            for (int r = 0; r < 4; r++) {
                int row = rb + r;
                float zv = acc[i][j][r] + bcol;
                if (row < M) {
                    C[(size_t)row * N + col] = zv;
                    cs += zv;
                    cq += zv * zv;
                }
            }
        }
        cs += __shfl_xor(cs, 16); cs += __shfl_xor(cs, 32);
        cq += __shfl_xor(cq, 16); cq += __shfl_xor(cq, 32);
        if (lquad == 0) {
            atomicAdd(&sums[col], cs);
            atomicAdd(&sumsq[col], cq);
        }
    }
}

// ================= BN apply + relu (finalize folded in): z fp32 -> h bf16 ==========

__global__ void bn_apply_raw(const float* __restrict__ z, const float* __restrict__ sums,
                             const float* __restrict__ sumsq, const float* __restrict__ gw,
                             const float* __restrict__ bw, float invM,
                             us_t* __restrict__ h, int n4, int fq_mask) {
    int i = blockIdx.x * blockDim.x + threadIdx.x;
    if (i >= n4) return;
    int f0 = (i & fq_mask) * 4;
    float4 sm = *(const float4*)&sums[f0];
    float4 sq = *(const float4*)&sumsq[f0];
    float4 gv = *(const float4*)&gw[f0];
    float4 bv = *(const float4*)&bw[f0];
    float4 v = *(const float4*)&z[(size_t)i * 4];
    us4 o;
    {
        float m = sm.x * invM, va = sq.x * invM - m * m;
        float s = gv.x * rsqrtf(va + BN_EPS), t = bv.x - m * s;
        o[0] = f2b(fmaxf(0.f, v.x * s + t));
    }
    {
        float m = sm.y * invM, va = sq.y * invM - m * m;
        float s = gv.y * rsqrtf(va + BN_EPS), t = bv.y - m * s;
        o[1] = f2b(fmaxf(0.f, v.y * s + t));
    }
    {
        float m = sm.z * invM, va = sq.z * invM - m * m;
        float s = gv.z * rsqrtf(va + BN_EPS), t = bv.z - m * s;
        o[2] = f2b(fmaxf(0.f, v.z * s + t));
    }
    {
        float m = sm.w * invM, va = sq.w * invM - m * m;
        float s = gv.w * rsqrtf(va + BN_EPS), t = bv.w - m * s;
        o[3] = f2b(fmaxf(0.f, v.w * s + t));
    }
    *(us4*)&h[(size_t)i * 4] = o;
}

// ================= pool (fp32 z in, BN finalize+apply+relu fused, atomic out) ==========

__global__ void pool_bn_raw(const float* __restrict__ z, const float* __restrict__ sums,
                            const float* __restrict__ sumsq, const float* __restrict__ gw,
                            const float* __restrict__ bw, float invM,
                            const int* __restrict__ batch, float* __restrict__ hg) {
    int f = threadIdx.x;  // 256
    float m = sums[f] * invM;
    float va = sumsq[f] * invM - m * m;
    float sv = gw[f] * rsqrtf(va + BN_EPS);
    float tv = bw[f] - m * sv;
    int n0 = blockIdx.x * 32;
    int n1 = min(n0 + 32, NNODES);
    float acc = 0.f;
    int gc = batch[n0];
    for (int n = n0; n < n1; n++) {
        int g = batch[n];
        if (g != gc) {
            atomicAdd(&hg[gc * 256 + f], acc);
            acc = 0.f;
            gc = g;
        }
        acc += fmaxf(0.f, z[(size_t)n * 256 + f] * sv + tv);
    }
    atomicAdd(&hg[gc * 256 + f], acc);
}

// ================= head GEMM fp32 (M=1000,K=256,N=128) + stats =================

#define GBM 128
#define GBN 128
#define GBK 16
#define LDA 132

__global__ __launch_bounds__(256) void gemm_f32_head(
    const float* __restrict__ A, const float* __restrict__ W, const float* __restrict__ bias,
    float* __restrict__ C, float* __restrict__ sums, float* __restrict__ sumsq,
    int M, int K, int N) {
    __shared__ float smem[2 * GBK * LDA];
    float* As = smem;
    float* Ws = smem + GBK * LDA;

    const int bm = blockIdx.y * GBM;
    const int bn = blockIdx.x * GBN;
    const int tid = threadIdx.x;
    const int tm = tid >> 4;
    const int tn = tid & 15;

    float acc[2][2][4][4] = {};

    for (int k0 = 0; k0 < K; k0 += GBK) {
        #pragma unroll
        for (int i = 0; i < 2; i++) {
            int id = tid + 256 * i;
            int row = id >> 2;
            int kq = id & 3;
            int gr = bm + row;
            int kk = k0 + kq * 4;
            float4 a4 = make_float4(0.f, 0.f, 0.f, 0.f);
            if (gr < M && kk < K) a4 = *(const float4*)&A[(size_t)gr * K + kk];
            As[(kq * 4 + 0) * LDA + row] = a4.x;
            As[(kq * 4 + 1) * LDA + row] = a4.y;
            As[(kq * 4 + 2) * LDA + row] = a4.z;
            As[(kq * 4 + 3) * LDA + row] = a4.w;
        }
        #pragma unroll
        for (int i = 0; i < 2; i++) {
            int id = tid + 256 * i;
            int kl = id >> 5;
            int c = id & 31;
            int kk = k0 + kl;
            float4 w4 = make_float4(0.f, 0.f, 0.f, 0.f);
            if (kk < K && bn + c * 4 < N) w4 = *(const float4*)&W[(size_t)kk * N + bn + c * 4];
            *(float4*)&Ws[kl * LDA + c * 4] = w4;
        }
        __syncthreads();
        #pragma unroll
        for (int k = 0; k < GBK; k++) {
            float4 a0 = *(float4*)&As[k * LDA + tm * 4];
            float4 a1 = *(float4*)&As[k * LDA + 64 + tm * 4];
            float4 w0 = *(float4*)&Ws[k * LDA + tn * 4];
            float4 w1 = *(float4*)&Ws[k * LDA + 64 + tn * 4];
            float ar[2][4] = {{a0.x, a0.y, a0.z, a0.w}, {a1.x, a1.y, a1.z, a1.w}};
            float wr[2][4] = {{w0.x, w0.y, w0.z, w0.w}, {w1.x, w1.y, w1.z, w1.w}};
            #pragma unroll
            for (int ri = 0; ri < 2; ri++)
                #pragma unroll
                for (int ci = 0; ci < 2; ci++)
                    #pragma unroll
                    for (int ii = 0; ii < 4; ii++)
                        #pragma unroll
                        for (int jj = 0; jj < 4; jj++)
                            acc[ri][ci][ii][jj] += ar[ri][ii] * wr[ci][jj];
        }
        __syncthreads();
    }

    float colsum[2][4] = {};
    float colsq[2][4] = {};
    #pragma unroll
    for (int ci = 0; ci < 2; ci++) {
        int colbase = bn + ci * 64 + tn * 4;
        if (colbase >= N) continue;
        float4 b4 = *(const float4*)&bias[colbase];
        float br[4] = {b4.x, b4.y, b4.z, b4.w};
        #pragma unroll
        for (int ri = 0; ri < 2; ri++) {
            #pragma unroll
            for (int ii = 0; ii < 4; ii++) {
                int row = bm + ri * 64 + tm * 4 + ii;
                if (row < M) {
                    float z0 = acc[ri][ci][ii][0] + br[0];
                    float z1 = acc[ri][ci][ii][1] + br[1];
                    float z2 = acc[ri][ci][ii][2] + br[2];
                    float z3 = acc[ri][ci][ii][3] + br[3];
                    *(float4*)&C[(size_t)row * N + colbase] = make_float4(z0, z1, z2, z3);
                    colsum[ci][0] += z0; colsq[ci][0] += z0 * z0;
                    colsum[ci][1] += z1; colsq[ci][1] += z1 * z1;
                    colsum[ci][2] += z2; colsq[ci][2] += z2 * z2;
                    colsum[ci][3] += z3; colsq[ci][3] += z3 * z3;
                }
            }
        }
    }
    __syncthreads();
    float* ps = smem;
    float* pq = smem + 2048;
    #pragma unroll
    for (int ci = 0; ci < 2; ci++)
        #pragma unroll
        for (int jj = 0; jj < 4; jj++) {
            int cl = ci * 64 + tn * 4 + jj;
            ps[tm * 128 + cl] = colsum[ci][jj];
            pq[tm * 128 + cl] = colsq[ci][jj];
        }
    __syncthreads();
    if (tid < 128 && bn + tid < N) {
        float s = 0.f, q = 0.f;
        #pragma unroll
        for (int i = 0; i < 16; i++) {
            s += ps[i * 128 + tid];
            q += pq[i * 128 + tid];
        }
        atomicAdd(&sums[bn + tid], s);
        atomicAdd(&sumsq[bn + tid], q);
    }
}

// ================= final head GEMV (BN finalize+apply+relu fused) =================

__global__ void final_gemv_raw(const float* __restrict__ hg2, const float* __restrict__ sums,
                               const float* __restrict__ sumsq, const float* __restrict__ gw,
                               const float* __restrict__ bw, float invM,
                               const float* __restrict__ fw2, const float* __restrict__ fb2,
                               float* __restrict__ out) {
    int g = blockIdx.x;
    int l = threadIdx.x;  // 64
    float m0 = sums[l] * invM, va0 = sumsq[l] * invM - m0 * m0;
    float s0 = gw[l] * rsqrtf(va0 + BN_EPS), t0 = bw[l] - m0 * s0;
    float m1 = sums[64 + l] * invM, va1 = sumsq[64 + l] * invM - m1 * m1;
    float s1 = gw[64 + l] * rsqrtf(va1 + BN_EPS), t1 = bw[64 + l] - m1 * s1;
    float a0 = fmaxf(0.f, hg2[g * 128 + l] * s0 + t0) * fw2[l];
    float a1 = fmaxf(0.f, hg2[g * 128 + 64 + l] * s1 + t1) * fw2[64 + l];
    float v = a0 + a1;
    #pragma unroll
    for (int o = 32; o > 0; o >>= 1) v += __shfl_down(v, o);
    if (l == 0) out[g] = v + fb2[0];
}

// ================= launch =================

extern "C" void kernel_launch(void* const* d_in, const int* in_sizes, int n_in,
                              void* d_out, int out_size, void* d_ws, size_t ws_size,
                              hipStream_t stream) {
    const float* x = (const float*)d_in[0];
    const int* ei = (const int*)d_in[1];
    const int* batch = (const int*)d_in[2];
    const int* esrc = ei;
    const int* edst = ei + NEDGES;

    const float* l1w = (const float*)d_in[3],  *l1b = (const float*)d_in[4],
               * l1g = (const float*)d_in[5],  *l1be = (const float*)d_in[6];
    const float* l2w = (const float*)d_in[7],  *l2b = (const float*)d_in[8],
               * l2g = (const float*)d_in[9],  *l2be = (const float*)d_in[10];
    const float* l3w = (const float*)d_in[11], *l3b = (const float*)d_in[12],
               * l3g = (const float*)d_in[13], *l3be = (const float*)d_in[14];
    const float* l4w = (const float*)d_in[15], *l4b = (const float*)d_in[16],
               * l4g = (const float*)d_in[17], *l4be = (const float*)d_in[18];
    const float* l5w = (const float*)d_in[19], *l5b = (const float*)d_in[20],
               * l5g = (const float*)d_in[21], *l5be = (const float*)d_in[22];
    const float* l6w = (const float*)d_in[23], *l6b = (const float*)d_in[24],
               * l6g = (const float*)d_in[25], *l6be = (const float*)d_in[26];
    const float* fw1 = (const float*)d_in[27], *fb1 = (const float*)d_in[28],
               * fg  = (const float*)d_in[29], *fbe = (const float*)d_in[30];
    const float* fw2 = (const float*)d_in[31], *fb2 = (const float*)d_in[32];

    // ---- workspace carve: two 51.2MB fp32 regions (ping-pong) + small stuff ----
    float* R0 = (float*)d_ws;                         // MPAD*256 fp32
    float* R1 = R0 + (size_t)MPAD * 256;              // MPAD*256 fp32
    us_t* R0h = (us_t*)R0;                            // bf16 view [M,256]
    us_t* R0a = R0h + (size_t)MPAD * 256;             // bf16 view, 2nd half
    us_t* R1h = (us_t*)R1;                            // bf16 view [M,128]
    us_t* R1a = R1h + (size_t)MPAD * 128;
    us_t* wt2 = (us_t*)(R1 + (size_t)MPAD * 256);     // [128][128]
    us_t* wt3 = wt2 + 128 * 128;                      // [256][128]
    us_t* wt4 = wt3 + 256 * 128;                      // [256][256]
    us_t* wt5 = wt4 + 256 * 256;
    us_t* wt6 = wt5 + 256 * 256;
    float* agg11 = (float*)(wt6 + 256 * 256);         // [50000][11]
    float* hg = agg11 + (size_t)NNODES * 11;          // [1000][256]
    float* hg2 = hg + NGRAPHS * 256;                  // [1000][128]
    float* stats = hg2 + NGRAPHS * 128;               // 7 x 512 (sums|sumsq)
    int* deg = (int*)(stats + 7 * 512);               // [50001]
    int* rowptr = deg + (NNODES + 1);
    int* cursor = rowptr + (NNODES + 1);
    int* chunkTot = cursor + (NNODES + 1);            // [64]
    int* tmpscan = chunkTot + 64;
    int* eidx = tmpscan + (NNODES + 1);               // [800000]

    // zero hg + hg2 + stats + deg (contiguous)
    {
        int zn = NGRAPHS * 256 + NGRAPHS * 128 + 7 * 512 + (NNODES + 1);
        zero_f32<<<(zn + 255) / 256, 256, 0, stream>>>(hg, zn);
    }

    // CSR
    csr_hist<<<(NEDGES + 255) / 256, 256, 0, stream>>>(edst, deg, NEDGES);
    int nchunks = (NNODES + 1023) / 1024;
    csr_scan1<<<nchunks, 1024, 0, stream>>>(deg, tmpscan, chunkTot, NNODES);
    csr_scan2<<<1, 64, 0, stream>>>(chunkTot, nchunks);
    csr_scan3<<<(NNODES + 255) / 256, 256, 0, stream>>>(deg, tmpscan, chunkTot, rowptr,
                                                        cursor, NNODES);
    csr_fill<<<(NEDGES + 255) / 256, 256, 0, stream>>>(esrc, edst, cursor, eidx, NEDGES);

    // weight converts (one kernel)
    wt_convert_all<<<(245760 + 255) / 256, 256, 0, stream>>>(l2w, l3w, l4w, l5w, l6w,
                                                             wt2, wt3, wt4, wt5, wt6);

    auto st = [&](int i) { return stats + i * 512; };
    const float invN = 1.0f / (float)NNODES;
    const float invG = 1.0f / (float)NGRAPHS;
    const int NRB = MPAD / 128;  // 391

    // ---- conv1: agg(x) -> z1=R0 -> [BN0 fused] l2 in-place -> z2=R0 ----
    gin_gather11<<<(NNODES + 15) / 16, 256, 0, stream>>>(x, rowptr, eidx, agg11);
    gemm11<<<(NNODES + 63) / 64, 256, 0, stream>>>(agg11, l1w, l1b, R0, st(0), st(0) + 256);
    gemm_v3<128, 1><<<dim3(1, NRB), 256, 0, stream>>>(
        R0, wt2, l2b, st(0), st(0) + 256, l1g, l1be, invN,
        R0, st(1), st(1) + 256, NNODES, 128);

    // ---- conv2: h2=R1h -> agg2=R1a -> z3=R0 -> [BN2 fused] l4 -> z4=R1 ----
    bn_apply_raw<<<(NNODES * 32 + 255) / 256, 256, 0, stream>>>(
        R0, st(1), st(1) + 256, l2g, l2be, invN, R1h, NNODES * 32, 31);
    gin_gather_bf<128><<<(NNODES + 7) / 8, 256, 0, stream>>>(R1h, rowptr, eidx, R1a);
    gemm_v3<128, 0><<<dim3(2, NRB), 256, 0, stream>>>(
        R1a, wt3, l3b, nullptr, nullptr, nullptr, nullptr, 0.f,
        R0, st(2), st(2) + 256, NNODES, 256);
    gemm_v3<256, 1><<<dim3(2, NRB), 256, 0, stream>>>(
        R0, wt4, l4b, st(2), st(2) + 256, l3g, l3be, invN,
        R1, st(3), st(3) + 256, NNODES, 256);

    // ---- conv3: h4=R0h -> agg3=R0a -> z5=R1 -> [BN4 fused] l6 -> z6=R0 ----
    bn_apply_raw<<<(NNODES * 64 + 255) / 256, 256, 0, stream>>>(
        R1, st(3), st(3) + 256, l4g, l4be, invN, R0h, NNODES * 64, 63);
    gin_gather_bf<256><<<(NNODES + 3) / 4, 256, 0, stream>>>(R0h, rowptr, eidx, R0a);
    gemm_v3<256, 0><<<dim3(2, NRB), 256, 0, stream>>>(
        R0a, wt5, l5b, nullptr, nullptr, nullptr, nullptr, 0.f,
        R1, st(4), st(4) + 256, NNODES, 256);
    gemm_v3<256, 1><<<dim3(2, NRB), 256, 0, stream>>>(
        R1, wt6, l6b, st(4), st(4) + 256, l5g, l5be, invN,
        R0, st(5), st(5) + 256, NNODES, 256);

    // ---- pool (BN5 fused) + head ----
    pool_bn_raw<<<(NNODES + 31) / 32, 256, 0, stream>>>(
        R0, st(5), st(5) + 256, l6g, l6be, invN, batch, hg);
    gemm_f32_head<<<dim3(1, 8), 256, 0, stream>>>(hg, fw1, fb1, hg2, st(6), st(6) + 256,
                                                  NGRAPHS, 256, 128);
    final_gemv_raw<<<NGRAPHS, 64, 0, stream>>>(hg2, st(6), st(6) + 256, fg, fbe, invG,
                                               fw2, fb2, (float*)d_out);
}

// Round 9
// 701.834 us; speedup vs baseline: 1.0100x; 1.0100x over previous
//
#include <hip/hip_runtime.h>

#define NNODES 50000
#define NEDGES 800000
#define NGRAPHS 1000
#define BN_EPS 1e-5f
#define MPAD 50048   // 391 * 128

typedef unsigned short us_t;
typedef us_t us8 __attribute__((ext_vector_type(8)));
typedef us_t us4 __attribute__((ext_vector_type(4)));
typedef __bf16 bf16x8 __attribute__((ext_vector_type(8)));
typedef float f32x4 __attribute__((ext_vector_type(4)));

__device__ __forceinline__ float b2f(us_t u) {
    union { unsigned int i; float f; } v;
    v.i = ((unsigned int)u) << 16;
    return v.f;
}
__device__ __forceinline__ us_t f2b(float x) {
    unsigned int u = __float_as_uint(x);
    unsigned int r = u + 0x7FFFu + ((u >> 16) & 1u);
    return (us_t)(r >> 16);
}
__device__ __forceinline__ bf16x8 as_bf(us8 v) {
    union { us8 u; bf16x8 b; } c;
    c.u = v;
    return c.b;
}

// ================= elementwise =================

__global__ void zero_f32(float* __restrict__ p, int n) {
    int i = blockIdx.x * blockDim.x + threadIdx.x;
    if (i < n) p[i] = 0.f;
}

// ================= CSR build =================

__global__ void csr_hist(const int* __restrict__ dst, int* __restrict__ deg, int E) {
    int e = blockIdx.x * blockDim.x + threadIdx.x;
    if (e < E) atomicAdd(&deg[dst[e]], 1);
}

__global__ void csr_scan1(const int* __restrict__ deg, int* __restrict__ tmpscan,
                          int* __restrict__ chunkTot, int n) {
    __shared__ int sm[1024];
    int i = blockIdx.x * 1024 + threadIdx.x;
    int v = (i < n) ? deg[i] : 0;
    sm[threadIdx.x] = v;
    __syncthreads();
    for (int off = 1; off < 1024; off <<= 1) {
        int add = (threadIdx.x >= off) ? sm[threadIdx.x - off] : 0;
        __syncthreads();
        sm[threadIdx.x] += add;
        __syncthreads();
    }
    if (i < n) tmpscan[i] = sm[threadIdx.x];
    if (threadIdx.x == 1023) chunkTot[blockIdx.x] = sm[1023];
}

__global__ void csr_scan2(int* __restrict__ chunkTot, int nchunks) {
    if (threadIdx.x == 0 && blockIdx.x == 0) {
        int run = 0;
        for (int c = 0; c < nchunks; c++) {
            int t = chunkTot[c];
            chunkTot[c] = run;
            run += t;
        }
    }
}

__global__ void csr_scan3(const int* __restrict__ deg, const int* __restrict__ tmpscan,
                          const int* __restrict__ chunkTot, int* __restrict__ rowptr,
                          int* __restrict__ cursor, int n) {
    int i = blockIdx.x * blockDim.x + threadIdx.x;
    if (i < n) {
        int inc = tmpscan[i] + chunkTot[i >> 10];
        rowptr[i + 1] = inc;
        cursor[i] = inc - deg[i];
        if (i == 0) rowptr[0] = 0;
    }
}

__global__ void csr_fill(const int* __restrict__ src, const int* __restrict__ dst,
                         int* __restrict__ cursor, int* __restrict__ eidx, int E) {
    int e = blockIdx.x * blockDim.x + threadIdx.x;
    if (e < E) {
        int pos = atomicAdd(&cursor[dst[e]], 1);
        eidx[pos] = src[e];
    }
}

// ================= all weight converts in one kernel: W[K][N] -> Wt[N][K] bf16 ==========

__global__ void wt_convert_all(const float* __restrict__ w2, const float* __restrict__ w3,
                               const float* __restrict__ w4, const float* __restrict__ w5,
                               const float* __restrict__ w6,
                               us_t* __restrict__ o2, us_t* __restrict__ o3,
                               us_t* __restrict__ o4, us_t* __restrict__ o5,
                               us_t* __restrict__ o6) {
    int i = blockIdx.x * blockDim.x + threadIdx.x;
    if (i < 16384) {                       // 128x128
        int k = i >> 7, n = i & 127;
        o2[n * 128 + k] = f2b(w2[i]);
    } else if (i < 49152) {                // 128x256
        int j = i - 16384; int k = j >> 8, n = j & 255;
        o3[n * 128 + k] = f2b(w3[j]);
    } else if (i < 114688) {               // 256x256
        int j = i - 49152; int k = j >> 8, n = j & 255;
        o4[n * 256 + k] = f2b(w4[j]);
    } else if (i < 180224) {
        int j = i - 114688; int k = j >> 8, n = j & 255;
        o5[n * 256 + k] = f2b(w5[j]);
    } else if (i < 245760) {
        int j = i - 180224; int k = j >> 8, n = j & 255;
        o6[n * 256 + k] = f2b(w6[j]);
    }
}

// ================= GIN gather with fused BN+relu (F=128, us4) =================
// out[n] = h(n) + sum_{j->n} h(j),  h = relu(z*s+t), z bf16, (s,t) from raw stats.

__global__ void gin_gather_bn128(const us_t* __restrict__ z, const float* __restrict__ sums,
                                 const float* __restrict__ sumsq, const float* __restrict__ gw,
                                 const float* __restrict__ bw, float invM,
                                 const int* __restrict__ rowptr, const int* __restrict__ eidx,
                                 us_t* __restrict__ out) {
    int ln = threadIdx.x >> 5;
    int fp = threadIdx.x & 31;
    int n = blockIdx.x * 8 + ln;
    if (n >= NNODES) return;
    int f0 = fp * 4;
    float s[4], t[4];
    #pragma unroll
    for (int q = 0; q < 4; q++) {
        float m = sums[f0 + q] * invM;
        float va = sumsq[f0 + q] * invM - m * m;
        s[q] = gw[f0 + q] * rsqrtf(va + BN_EPS);
        t[q] = bw[f0 + q] - m * s[q];
    }
    const us_t* zf = z + f0;
    float a[4];
    us4 v = *(const us4*)&zf[(size_t)n * 128];
    #pragma unroll
    for (int q = 0; q < 4; q++) a[q] = fmaxf(0.f, b2f(v[q]) * s[q] + t[q]);
    int p0 = rowptr[n], p1 = rowptr[n + 1];
    int p = p0;
    for (; p + 4 <= p1; p += 4) {
        int e0 = eidx[p], e1 = eidx[p + 1], e2 = eidx[p + 2], e3 = eidx[p + 3];
        us4 u0 = *(const us4*)&zf[(size_t)e0 * 128];
        us4 u1 = *(const us4*)&zf[(size_t)e1 * 128];
        us4 u2 = *(const us4*)&zf[(size_t)e2 * 128];
        us4 u3 = *(const us4*)&zf[(size_t)e3 * 128];
        #pragma unroll
        for (int q = 0; q < 4; q++)
            a[q] += fmaxf(0.f, b2f(u0[q]) * s[q] + t[q]) +
                    fmaxf(0.f, b2f(u1[q]) * s[q] + t[q]) +
                    fmaxf(0.f, b2f(u2[q]) * s[q] + t[q]) +
                    fmaxf(0.f, b2f(u3[q]) * s[q] + t[q]);
    }
    for (; p < p1; p++) {
        us4 u = *(const us4*)&zf[(size_t)eidx[p] * 128];
        #pragma unroll
        for (int q = 0; q < 4; q++) a[q] += fmaxf(0.f, b2f(u[q]) * s[q] + t[q]);
    }
    us4 o;
    #pragma unroll
    for (int q = 0; q < 4; q++) o[q] = f2b(a[q]);
    *(us4*)&out[(size_t)n * 128 + f0] = o;
}

// ================= GIN gather with fused BN+relu (F=256, us8 / 16B lanes) ==========

__global__ void gin_gather_bn256(const us_t* __restrict__ z, const float* __restrict__ sums,
                                 const float* __restrict__ sumsq, const float* __restrict__ gw,
                                 const float* __restrict__ bw, float invM,
                                 const int* __restrict__ rowptr, const int* __restrict__ eidx,
                                 us_t* __restrict__ out) {
    int ln = threadIdx.x >> 5;       // 0..7
    int fp = threadIdx.x & 31;
    int n = blockIdx.x * 8 + ln;
    if (n >= NNODES) return;
    int f0 = fp * 8;
    float s[8], t[8];
    #pragma unroll
    for (int q = 0; q < 8; q++) {
        float m = sums[f0 + q] * invM;
        float va = sumsq[f0 + q] * invM - m * m;
        s[q] = gw[f0 + q] * rsqrtf(va + BN_EPS);
        t[q] = bw[f0 + q] - m * s[q];
    }
    const us_t* zf = z + f0;
    float a[8];
    us8 v = *(const us8*)&zf[(size_t)n * 256];
    #pragma unroll
    for (int q = 0; q < 8; q++) a[q] = fmaxf(0.f, b2f(v[q]) * s[q] + t[q]);
    int p0 = rowptr[n], p1 = rowptr[n + 1];
    int p = p0;
    for (; p + 4 <= p1; p += 4) {
        int e0 = eidx[p], e1 = eidx[p + 1], e2 = eidx[p + 2], e3 = eidx[p + 3];
        us8 u0 = *(const us8*)&zf[(size_t)e0 * 256];
        us8 u1 = *(const us8*)&zf[(size_t)e1 * 256];
        us8 u2 = *(const us8*)&zf[(size_t)e2 * 256];
        us8 u3 = *(const us8*)&zf[(size_t)e3 * 256];
        #pragma unroll
        for (int q = 0; q < 8; q++)
            a[q] += fmaxf(0.f, b2f(u0[q]) * s[q] + t[q]) +
                    fmaxf(0.f, b2f(u1[q]) * s[q] + t[q]) +
                    fmaxf(0.f, b2f(u2[q]) * s[q] + t[q]) +
                    fmaxf(0.f, b2f(u3[q]) * s[q] + t[q]);
    }
    for (; p < p1; p++) {
        us8 u = *(const us8*)&zf[(size_t)eidx[p] * 256];
        #pragma unroll
        for (int q = 0; q < 8; q++) a[q] += fmaxf(0.f, b2f(u[q]) * s[q] + t[q]);
    }
    us8 o;
    #pragma unroll
    for (int q = 0; q < 8; q++) o[q] = f2b(a[q]);
    *(us8*)&out[(size_t)n * 256 + f0] = o;
}

// F=11 fp32 gather (input features)
__global__ void gin_gather11(const float* __restrict__ x, const int* __restrict__ rowptr,
                             const int* __restrict__ eidx, float* __restrict__ out) {
    int local = threadIdx.x >> 4;
    int lane = threadIdx.x & 15;
    int n = blockIdx.x * 16 + local;
    if (n >= NNODES) return;
    int p0 = rowptr[n], p1 = rowptr[n + 1];
    float acc = (lane < 11) ? x[n * 11 + lane] : 0.f;
    for (int p = p0; p < p1; p++) {
        int src = eidx[p];
        if (lane < 11) acc += x[src * 11 + lane];
    }
    if (lane < 11) out[n * 11 + lane] = acc;
}

// ================= layer-1 GEMM: [M,11] fp32 @ [11,128] + b -> fp32 + stats ==========

__global__ __launch_bounds__(256) void gemm11(const float* __restrict__ A,
                                              const float* __restrict__ W,
                                              const float* __restrict__ b,
                                              float* __restrict__ C,
                                              float* __restrict__ sums,
                                              float* __restrict__ sumsq) {
    __shared__ float sW[11 * 128];
    __shared__ float sArows[64 * 11];
    int tid = threadIdx.x;
    for (int i = tid; i < 11 * 128; i += 256) sW[i] = W[i];
    int r0 = blockIdx.x * 64;
    for (int i = tid; i < 64 * 11; i += 256) {
        int r = i / 11, c = i - r * 11;
        sArows[i] = (r0 + r < NNODES) ? A[(r0 + r) * 11 + c] : 0.f;
    }
    __syncthreads();
    int col = tid & 127;
    int half = tid >> 7;
    float bias = b[col];
    float cs = 0.f, cq = 0.f;
    for (int rr = half * 32; rr < half * 32 + 32; rr++) {
        int row = r0 + rr;
        if (row < NNODES) {
            float acc = bias;
            #pragma unroll
            for (int k = 0; k < 11; k++) acc += sArows[rr * 11 + k] * sW[k * 128 + col];
            C[(size_t)row * 128 + col] = acc;
            cs += acc;
            cq += acc * acc;
        }
    }
    __syncthreads();
    sArows[tid] = cs;
    sArows[256 + tid] = cq;
    __syncthreads();
    if (tid < 128) {
        atomicAdd(&sums[tid], sArows[tid] + sArows[tid + 128]);
        atomicAdd(&sumsq[tid], sArows[256 + tid] + sArows[256 + tid + 128]);
    }
}

// ================= MFMA GEMM v5 =================
// C[M,N] = A'[M,K_] @ Wt[N,K_]^T + bias, + exact column stats (from fp32 acc).
// AMODE 0: A bf16, used directly.
// AMODE 1: A fp32; A' = relu(A*s+t)->bf16 in staging, (s,t) from raw stats (LDS).
// OMODE 0: C bf16.  OMODE 1: C fp32.
// No B LDS (L2-resident), zero K-loop barriers, high occupancy.

template <int K_, int AMODE, int OMODE>
__global__ __launch_bounds__(256, 4) void gemm_v5(
    const void* __restrict__ Ap, const us_t* __restrict__ Wt,
    const float* __restrict__ bias,
    const float* __restrict__ sums_in, const float* __restrict__ sumsq_in,
    const float* __restrict__ gma, const float* __restrict__ bet, float invM,
    void* __restrict__ Cp, float* __restrict__ sums, float* __restrict__ sumsq,
    int M, int N) {
    __shared__ float sST[2 * K_];          // [s | t]

    const int tid = threadIdx.x;
    const int lane = tid & 63;
    const int wave = tid >> 6;
    const int wm = wave >> 1, wn = wave & 1;
    const int bn = blockIdx.x * 128;
    const int bm = blockIdx.y * 128;
    const int lrow = lane & 15, lquad = lane >> 4;

    if (AMODE == 1) {
        if (tid < K_) {
            float m = sums_in[tid] * invM;
            float va = sumsq_in[tid] * invM - m * m;
            float sc = gma[tid] * rsqrtf(va + BN_EPS);
            sST[tid] = sc;
            sST[K_ + tid] = bet[tid] - m * sc;
        }
        __syncthreads();
    }

    f32x4 acc[4][4] = {};

    size_t arow[4];
    #pragma unroll
    for (int i = 0; i < 4; i++) arow[i] = (size_t)(bm + wm * 64 + i * 16 + lrow) * K_;
    size_t brow[4];
    #pragma unroll
    for (int j = 0; j < 4; j++) brow[j] = (size_t)(bn + wn * 64 + j * 16 + lrow) * K_;

    #pragma unroll
    for (int kt = 0; kt < K_ / 32; kt++) {
        const int kq = kt * 32 + lquad * 8;
        bf16x8 af[4], bfr[4];
        if (AMODE == 0) {
            const us_t* A = (const us_t*)Ap;
            #pragma unroll
            for (int i = 0; i < 4; i++)
                af[i] = as_bf(*(const us8*)&A[arow[i] + kq]);
        } else {
            const float* A = (const float*)Ap;
            float4 s0 = *(const float4*)&sST[kq];
            float4 s1 = *(const float4*)&sST[kq + 4];
            float4 t0 = *(const float4*)&sST[K_ + kq];
            float4 t1 = *(const float4*)&sST[K_ + kq + 4];
            #pragma unroll
            for (int i = 0; i < 4; i++) {
                const float* ar = &A[arow[i] + kq];
                float4 v0 = *(const float4*)ar;
                float4 v1 = *(const float4*)(ar + 4);
                union { us8 u; bf16x8 b; } cv;
                cv.u[0] = f2b(fmaxf(0.f, v0.x * s0.x + t0.x));
                cv.u[1] = f2b(fmaxf(0.f, v0.y * s0.y + t0.y));
                cv.u[2] = f2b(fmaxf(0.f, v0.z * s0.z + t0.z));
                cv.u[3] = f2b(fmaxf(0.f, v0.w * s0.w + t0.w));
                cv.u[4] = f2b(fmaxf(0.f, v1.x * s1.x + t1.x));
                cv.u[5] = f2b(fmaxf(0.f, v1.y * s1.y + t1.y));
                cv.u[6] = f2b(fmaxf(0.f, v1.z * s1.z + t1.z));
                cv.u[7] = f2b(fmaxf(0.f, v1.w * s1.w + t1.w));
                af[i] = cv.b;
            }
        }
        #pragma unroll
        for (int j = 0; j < 4; j++)
            bfr[j] = as_bf(*(const us8*)&Wt[brow[j] + kq]);
        #pragma unroll
        for (int i = 0; i < 4; i++)
            #pragma unroll
            for (int j = 0; j < 4; j++)
                acc[i][j] = __builtin_amdgcn_mfma_f32_16x16x32_bf16(af[i], bfr[j],
                                                                    acc[i][j], 0, 0, 0);
    }

    // ---- epilogue: bias, store, exact column stats ----
    #pragma unroll
    for (int j = 0; j < 4; j++) {
        int col = bn + wn * 64 + j * 16 + lrow;
        float bcol = bias[col];
        float cs = 0.f, cq = 0.f;
        #pragma unroll
        for (int i = 0; i < 4; i++) {
            int rb = bm + wm * 64 + i * 16 + lquad * 4;
            #pragma unroll
            for (int r = 0; r < 4; r++) {
                int row = rb + r;
                float zv = acc[i][j][r] + bcol;
                if (row < M) {
                    if (OMODE == 0)
                        ((us_t*)Cp)[(size_t)row * N + col] = f2b(zv);
                    else
                        ((float*)Cp)[(size_t)row * N + col] = zv;
                    cs += zv;
                    cq += zv * zv;
                }
            }
        }
        cs += __shfl_xor(cs, 16); cs += __shfl_xor(cs, 32);
        cq += __shfl_xor(cq, 16); cq += __shfl_xor(cq, 32);
        if (lquad == 0) {
            atomicAdd(&sums[col], cs);
            atomicAdd(&sumsq[col], cq);
        }
    }
}

// ================= pool (fp32 z in, BN finalize+apply+relu fused, atomic out) ==========

__global__ void pool_bn_raw(const float* __restrict__ z, const float* __restrict__ sums,
                            const float* __restrict__ sumsq, const float* __restrict__ gw,
                            const float* __restrict__ bw, float invM,
                            const int* __restrict__ batch, float* __restrict__ hg) {
    int f = threadIdx.x;  // 256
    float m = sums[f] * invM;
    float va = sumsq[f] * invM - m * m;
    float sv = gw[f] * rsqrtf(va + BN_EPS);
    float tv = bw[f] - m * sv;
    int n0 = blockIdx.x * 32;
    int n1 = min(n0 + 32, NNODES);
    float acc = 0.f;
    int gc = batch[n0];
    for (int n = n0; n < n1; n++) {
        int g = batch[n];
        if (g != gc) {
            atomicAdd(&hg[gc * 256 + f], acc);
            acc = 0.f;
            gc = g;
        }
        acc += fmaxf(0.f, z[(size_t)n * 256 + f] * sv + tv);
    }
    atomicAdd(&hg[gc * 256 + f], acc);
}

// ================= head GEMM fp32 (M=1000,K=256,N=128) + stats =================

#define GBM 128
#define GBN 128
#define GBK 16
#define LDA 132

__global__ __launch_bounds__(256) void gemm_f32_head(
    const float* __restrict__ A, const float* __restrict__ W, const float* __restrict__ bias,
    float* __restrict__ C, float* __restrict__ sums, float* __restrict__ sumsq,
    int M, int K, int N) {
    __shared__ float smem[2 * GBK * LDA];
    float* As = smem;
    float* Ws = smem + GBK * LDA;

    const int bm = blockIdx.y * GBM;
    const int bn = blockIdx.x * GBN;
    const int tid = threadIdx.x;
    const int tm = tid >> 4;
    const int tn = tid & 15;

    float acc[2][2][4][4] = {};

    for (int k0 = 0; k0 < K; k0 += GBK) {
        #pragma unroll
        for (int i = 0; i < 2; i++) {
            int id = tid + 256 * i;
            int row = id >> 2;
            int kq = id & 3;
            int gr = bm + row;
            int kk = k0 + kq * 4;
            float4 a4 = make_float4(0.f, 0.f, 0.f, 0.f);
            if (gr < M && kk < K) a4 = *(const float4*)&A[(size_t)gr * K + kk];
            As[(kq * 4 + 0) * LDA + row] = a4.x;
            As[(kq * 4 + 1) * LDA + row] = a4.y;
            As[(kq * 4 + 2) * LDA + row] = a4.z;
            As[(kq * 4 + 3) * LDA + row] = a4.w;
        }
        #pragma unroll
        for (int i = 0; i < 2; i++) {
            int id = tid + 256 * i;
            int kl = id >> 5;
            int c = id & 31;
            int kk = k0 + kl;
            float4 w4 = make_float4(0.f, 0.f, 0.f, 0.f);
            if (kk < K && bn + c * 4 < N) w4 = *(const float4*)&W[(size_t)kk * N + bn + c * 4];
            *(float4*)&Ws[kl * LDA + c * 4] = w4;
        }
        __syncthreads();
        #pragma unroll
        for (int k = 0; k < GBK; k++) {
            float4 a0 = *(float4*)&As[k * LDA + tm * 4];
            float4 a1 = *(float4*)&As[k * LDA + 64 + tm * 4];
            float4 w0 = *(float4*)&Ws[k * LDA + tn * 4];
            float4 w1 = *(float4*)&Ws[k * LDA + 64 + tn * 4];
            float ar[2][4] = {{a0.x, a0.y, a0.z, a0.w}, {a1.x, a1.y, a1.z, a1.w}};
            float wr[2][4] = {{w0.x, w0.y, w0.z, w0.w}, {w1.x, w1.y, w1.z, w1.w}};
            #pragma unroll
            for (int ri = 0; ri < 2; ri++)
                #pragma unroll
                for (int ci = 0; ci < 2; ci++)
                    #pragma unroll
                    for (int ii = 0; ii < 4; ii++)
                        #pragma unroll
                        for (int jj = 0; jj < 4; jj++)
                            acc[ri][ci][ii][jj] += ar[ri][ii] * wr[ci][jj];
        }
        __syncthreads();
    }

    float colsum[2][4] = {};
    float colsq[2][4] = {};
    #pragma unroll
    for (int ci = 0; ci < 2; ci++) {
        int colbase = bn + ci * 64 + tn * 4;
        if (colbase >= N) continue;
        float4 b4 = *(const float4*)&bias[colbase];
        float br[4] = {b4.x, b4.y, b4.z, b4.w};
        #pragma unroll
        for (int ri = 0; ri < 2; ri++) {
            #pragma unroll
            for (int ii = 0; ii < 4; ii++) {
                int row = bm + ri * 64 + tm * 4 + ii;
                if (row < M) {
                    float z0 = acc[ri][ci][ii][0] + br[0];
                    float z1 = acc[ri][ci][ii][1] + br[1];
                    float z2 = acc[ri][ci][ii][2] + br[2];
                    float z3 = acc[ri][ci][ii][3] + br[3];
                    *(float4*)&C[(size_t)row * N + colbase] = make_float4(z0, z1, z2, z3);
                    colsum[ci][0] += z0; colsq[ci][0] += z0 * z0;
                    colsum[ci][1] += z1; colsq[ci][1] += z1 * z1;
                    colsum[ci][2] += z2; colsq[ci][2] += z2 * z2;
                    colsum[ci][3] += z3; colsq[ci][3] += z3 * z3;
                }
            }
        }
    }
    __syncthreads();
    float* ps = smem;
    float* pq = smem + 2048;
    #pragma unroll
    for (int ci = 0; ci < 2; ci++)
        #pragma unroll
        for (int jj = 0; jj < 4; jj++) {
            int cl = ci * 64 + tn * 4 + jj;
            ps[tm * 128 + cl] = colsum[ci][jj];
            pq[tm * 128 + cl] = colsq[ci][jj];
        }
    __syncthreads();
    if (tid < 128 && bn + tid < N) {
        float s = 0.f, q = 0.f;
        #pragma unroll
        for (int i = 0; i < 16; i++) {
            s += ps[i * 128 + tid];
            q += pq[i * 128 + tid];
        }
        atomicAdd(&sums[bn + tid], s);
        atomicAdd(&sumsq[bn + tid], q);
    }
}

// ================= final head GEMV (BN finalize+apply+relu fused) =================

__global__ void final_gemv_raw(const float* __restrict__ hg2, const float* __restrict__ sums,
                               const float* __restrict__ sumsq, const float* __restrict__ gw,
                               const float* __restrict__ bw, float invM,
                               const float* __restrict__ fw2, const float* __restrict__ fb2,
                               float* __restrict__ out) {
    int g = blockIdx.x;
    int l = threadIdx.x;  // 64
    float m0 = sums[l] * invM, va0 = sumsq[l] * invM - m0 * m0;
    float s0 = gw[l] * rsqrtf(va0 + BN_EPS), t0 = bw[l] - m0 * s0;
    float m1 = sums[64 + l] * invM, va1 = sumsq[64 + l] * invM - m1 * m1;
    float s1 = gw[64 + l] * rsqrtf(va1 + BN_EPS), t1 = bw[64 + l] - m1 * s1;
    float a0 = fmaxf(0.f, hg2[g * 128 + l] * s0 + t0) * fw2[l];
    float a1 = fmaxf(0.f, hg2[g * 128 + 64 + l] * s1 + t1) * fw2[64 + l];
    float v = a0 + a1;
    #pragma unroll
    for (int o = 32; o > 0; o >>= 1) v += __shfl_down(v, o);
    if (l == 0) out[g] = v + fb2[0];
}

// ================= launch =================

extern "C" void kernel_launch(void* const* d_in, const int* in_sizes, int n_in,
                              void* d_out, int out_size, void* d_ws, size_t ws_size,
                              hipStream_t stream) {
    const float* x = (const float*)d_in[0];
    const int* ei = (const int*)d_in[1];
    const int* batch = (const int*)d_in[2];
    const int* esrc = ei;
    const int* edst = ei + NEDGES;

    const float* l1w = (const float*)d_in[3],  *l1b = (const float*)d_in[4],
               * l1g = (const float*)d_in[5],  *l1be = (const float*)d_in[6];
    const float* l2w = (const float*)d_in[7],  *l2b = (const float*)d_in[8],
               * l2g = (const float*)d_in[9],  *l2be = (const float*)d_in[10];
    const float* l3w = (const float*)d_in[11], *l3b = (const float*)d_in[12],
               * l3g = (const float*)d_in[13], *l3be = (const float*)d_in[14];
    const float* l4w = (const float*)d_in[15], *l4b = (const float*)d_in[16],
               * l4g = (const float*)d_in[17], *l4be = (const float*)d_in[18];
    const float* l5w = (const float*)d_in[19], *l5b = (const float*)d_in[20],
               * l5g = (const float*)d_in[21], *l5be = (const float*)d_in[22];
    const float* l6w = (const float*)d_in[23], *l6b = (const float*)d_in[24],
               * l6g = (const float*)d_in[25], *l6be = (const float*)d_in[26];
    const float* fw1 = (const float*)d_in[27], *fb1 = (const float*)d_in[28],
               * fg  = (const float*)d_in[29], *fbe = (const float*)d_in[30];
    const float* fw2 = (const float*)d_in[31], *fb2 = (const float*)d_in[32];

    // ---- workspace carve ----
    // F0: fp32 [MPAD,256]  (z1 [M,128] -> z3 -> z5)
    // U : fp32 [MPAD,256] region, overlaid:
    //      Ba = (us_t*)U           [MPAD,256] bf16  (agg buffers)
    //      Bz = Ba + MPAD*256      [MPAD,256] bf16  (z2/z4)
    //      F1 = (float*)U          [MPAD,256] fp32  (z6, after Ba/Bz dead)
    float* F0 = (float*)d_ws;
    float* F1 = F0 + (size_t)MPAD * 256;
    us_t* Ba = (us_t*)F1;
    us_t* Bz = Ba + (size_t)MPAD * 256;
    us_t* wt2 = (us_t*)(F1 + (size_t)MPAD * 256);     // [128][128]
    us_t* wt3 = wt2 + 128 * 128;                      // [256][128]
    us_t* wt4 = wt3 + 256 * 128;                      // [256][256]
    us_t* wt5 = wt4 + 256 * 256;
    us_t* wt6 = wt5 + 256 * 256;
    float* agg11 = (float*)(wt6 + 256 * 256);         // [50000][11]
    float* hg = agg11 + (size_t)NNODES * 11;          // [1000][256]
    float* hg2 = hg + NGRAPHS * 256;                  // [1000][128]
    float* stats = hg2 + NGRAPHS * 128;               // 7 x 512 (sums|sumsq)
    int* deg = (int*)(stats + 7 * 512);               // [50001]
    int* rowptr = deg + (NNODES + 1);
    int* cursor = rowptr + (NNODES + 1);
    int* chunkTot = cursor + (NNODES + 1);            // [64]
    int* tmpscan = chunkTot + 64;
    int* eidx = tmpscan + (NNODES + 1);               // [800000]

    // zero hg + hg2 + stats + deg (contiguous)
    {
        int zn = NGRAPHS * 256 + NGRAPHS * 128 + 7 * 512 + (NNODES + 1);
        zero_f32<<<(zn + 255) / 256, 256, 0, stream>>>(hg, zn);
    }

    // CSR
    csr_hist<<<(NEDGES + 255) / 256, 256, 0, stream>>>(edst, deg, NEDGES);
    int nchunks = (NNODES + 1023) / 1024;
    csr_scan1<<<nchunks, 1024, 0, stream>>>(deg, tmpscan, chunkTot, NNODES);
    csr_scan2<<<1, 64, 0, stream>>>(chunkTot, nchunks);
    csr_scan3<<<(NNODES + 255) / 256, 256, 0, stream>>>(deg, tmpscan, chunkTot, rowptr,
                                                        cursor, NNODES);
    csr_fill<<<(NEDGES + 255) / 256, 256, 0, stream>>>(esrc, edst, cursor, eidx, NEDGES);

    // weight converts
    wt_convert_all<<<(245760 + 255) / 256, 256, 0, stream>>>(l2w, l3w, l4w, l5w, l6w,
                                                             wt2, wt3, wt4, wt5, wt6);

    auto st = [&](int i) { return stats + i * 512; };
    const float invN = 1.0f / (float)NNODES;
    const float invG = 1.0f / (float)NGRAPHS;
    const int NRB = MPAD / 128;  // 391

    // ---- conv1: agg(x) -> z1=F0 fp32 [M,128] -> [BN0 fused] l2 -> z2=Bz bf16 ----
    gin_gather11<<<(NNODES + 15) / 16, 256, 0, stream>>>(x, rowptr, eidx, agg11);
    gemm11<<<(NNODES + 63) / 64, 256, 0, stream>>>(agg11, l1w, l1b, F0, st(0), st(0) + 256);
    gemm_v5<128, 1, 0><<<dim3(1, NRB), 256, 0, stream>>>(
        F0, wt2, l2b, st(0), st(0) + 256, l1g, l1be, invN,
        Bz, st(1), st(1) + 256, NNODES, 128);

    // ---- conv2: gather(BN1) z2 -> agg2=Ba bf16 [M,128] -> l3 -> z3=F0 fp32 [M,256]
    //            -> [BN2 fused] l4 -> z4=Bz bf16 [M,256] ----
    gin_gather_bn128<<<(NNODES + 7) / 8, 256, 0, stream>>>(
        Bz, st(1), st(1) + 256, l2g, l2be, invN, rowptr, eidx, Ba);
    gemm_v5<128, 0, 1><<<dim3(2, NRB), 256, 0, stream>>>(
        Ba, wt3, l3b, nullptr, nullptr, nullptr, nullptr, 0.f,
        F0, st(2), st(2) + 256, NNODES, 256);
    gemm_v5<256, 1, 0><<<dim3(2, NRB), 256, 0, stream>>>(
        F0, wt4, l4b, st(2), st(2) + 256, l3g, l3be, invN,
        Bz, st(3), st(3) + 256, NNODES, 256);

    // ---- conv3: gather(BN3) z4 -> agg3=Ba bf16 [M,256] -> l5 -> z5=F0 fp32
    //            -> [BN4 fused] l6 -> z6=F1 fp32 (Ba/Bz dead) ----
    gin_gather_bn256<<<(NNODES + 7) / 8, 256, 0, stream>>>(
        Bz, st(3), st(3) + 256, l4g, l4be, invN, rowptr, eidx, Ba);
    gemm_v5<256, 0, 1><<<dim3(2, NRB), 256, 0, stream>>>(
        Ba, wt5, l5b, nullptr, nullptr, nullptr, nullptr, 0.f,
        F0, st(4), st(4) + 256, NNODES, 256);
    gemm_v5<256, 1, 1><<<dim3(2, NRB), 256, 0, stream>>>(
        F0, wt6, l6b, st(4), st(4) + 256, l5g, l5be, invN,
        F1, st(5), st(5) + 256, NNODES, 256);

    // ---- pool (BN5 fused) + head ----
    pool_bn_raw<<<(NNODES + 31) / 32, 256, 0, stream>>>(
        F1, st(5), st(5) + 256, l6g, l6be, invN, batch, hg);
    gemm_f32_head<<<dim3(1, 8), 256, 0, stream>>>(hg, fw1, fb1, hg2, st(6), st(6) + 256,
                                                  NGRAPHS, 256, 128);
    final_gemv_raw<<<NGRAPHS, 64, 0, stream>>>(hg2, st(6), st(6) + 256, fg, fbe, invG,
                                               fw2, fb2, (float*)d_out);
}